// Round 8
// baseline (955.884 us; speedup 1.0000x reference)
//
#include <hip/hip_runtime.h>
#include <math.h>

// SpikingPendulumBrain — single persistent kernel.
//  * W_rec as two int8 planes (exact int32 MFMA; validated absmax 0.0 in
//    rounds 2/4/5/6). Each wave holds its B fragments in 32 VGPRs for the
//    whole 50 steps -> zero per-step weight traffic.
//  * v/isyn/iin in registers (1 element per thread). Only spikes cross
//    blocks: bit-packed, one 64KB buffer per step, accessed exclusively via
//    relaxed agent-scope atomics (bypass non-coherent per-XCD L2s; also
//    dodges stale poison-fill lines in L2).
//  * Hand-rolled global barrier (release fetch_add + relaxed poll + s_sleep)
//    instead of cooperative grid.sync (measured ~65us/sync in round 4).
//  * Fallback: round-6 proven multi-launch path if coop launch is rejected.

#define NN 4096
#define BB 64
#define STEPS 50
#define NBLK 256
#define NPB 16
#define PKROW 256                    // dwords per packed row (uint32 per 16 cols)
#define PKSTEP (BB * PKROW)          // dwords per step buffer

typedef __attribute__((ext_vector_type(4))) int i32x4;

static constexpr float WMAX_C = 0.16f;
static constexpr float QHI_C  = WMAX_C / 127.0f;
static constexpr float QLO_C  = QHI_C / 256.0f;
static constexpr float SYNDEC = (float)0.9801986733067553;  // exp(-0.1/5)

// ---------------- one-time prep (re-run every call; ws is re-poisoned) -----

__global__ __launch_bounds__(256) void quant_kernel(const float* __restrict__ W,
                                                    signed char* __restrict__ Ph,
                                                    signed char* __restrict__ Pl,
                                                    unsigned* __restrict__ cnt) {
  int idx = blockIdx.x * 256 + threadIdx.x;
  float4 w4 = reinterpret_cast<const float4*>(W)[idx];
  float w[4] = {w4.x, w4.y, w4.z, w4.w};
  signed char hi[4], lo[4];
#pragma unroll
  for (int i = 0; i < 4; i++) {
    float h = rintf(w[i] * (1.0f / QHI_C));
    h = fminf(127.0f, fmaxf(-127.0f, h));
    float r = fmaf(h, -QHI_C, w[i]);
    float l = rintf(r * (1.0f / QLO_C));
    l = fminf(127.0f, fmaxf(-127.0f, l));
    hi[i] = (signed char)(int)h;
    lo[i] = (signed char)(int)l;
  }
  reinterpret_cast<char4*>(Ph)[idx] = make_char4(hi[0], hi[1], hi[2], hi[3]);
  reinterpret_cast<char4*>(Pl)[idx] = make_char4(lo[0], lo[1], lo[2], lo[3]);
  if (idx == 0) *cnt = 0;            // barrier counter (flushed at kernel end)
}

// ---------------- helpers ---------------------------------------------------

__device__ __forceinline__ i32x4 expand16(unsigned h) {
  // 16 bits -> 16 bytes (0/1): nibble q -> dword q via bit-spread multiply
  i32x4 a;
#pragma unroll
  for (int q = 0; q < 4; ++q) {
    unsigned nib = (h >> (4 * q)) & 0xFu;
    a[q] = (int)((nib * 0x00204081u) & 0x01010101u);
  }
  return a;
}

__device__ __forceinline__ void gbar(unsigned* cnt, unsigned tgt) {
  asm volatile("s_waitcnt vmcnt(0)" ::: "memory");   // drain this thread's stores
  __syncthreads();                                   // all waves drained
  if (threadIdx.x == 0) {
    __hip_atomic_fetch_add(cnt, 1u, __ATOMIC_RELEASE, __HIP_MEMORY_SCOPE_AGENT);
    while (__hip_atomic_load(cnt, __ATOMIC_RELAXED, __HIP_MEMORY_SCOPE_AGENT) < tgt)
      __builtin_amdgcn_s_sleep(1);
  }
  __syncthreads();
}

// ---------------- persistent brain kernel ----------------------------------
// 256 blocks x 1024 threads (16 waves, 1 block/CU). Block owns neurons
// [blk*16, +16), all 64 batch rows, full K. Wave w owns K-slice [w*256,+256)
// with its B fragments HELD IN REGISTERS across all steps. Spikes cross
// blocks as packed bits: pk[s][row][blk16] uint32 (low 16 bits).

__global__ __launch_bounds__(1024, 1) void brain2(
    const signed char* __restrict__ Ph,
    const signed char* __restrict__ Pl,
    const float* __restrict__ obs,
    const float* __restrict__ Win,
    unsigned* __restrict__ pk,
    unsigned* __restrict__ cnt) {
  const int blk = blockIdx.x;
  const int n0  = blk * NPB;
  const int t   = threadIdx.x;
  const int lane = t & 63;
  const int w    = t >> 6;
  const int l15  = lane & 15, lhi = lane >> 4;
  const int ob   = t >> 4;          // owned batch row
  const int on   = t & 15;          // owned neuron (within block)

  __shared__ i32x4 red[16][4][64];  // 64KB cross-wave int32 partials

  // per-thread state in registers
  float iin = 5.0f * (obs[ob * 2 + 0] * Win[(n0 + on) * 2 + 0] +
                      obs[ob * 2 + 1] * Win[(n0 + on) * 2 + 1]);
  float v = 0.0f, isyn = 0.0f;

  // B fragments held for the whole kernel: 4 kc x 2 planes x i32x4
  const signed char* bhp = Ph + (size_t)(n0 + l15) * NN + w * 256 + lhi * 16;
  const signed char* blp = Pl + (size_t)(n0 + l15) * NN + w * 256 + lhi * 16;
  i32x4 Bh[4], Bl[4];
#pragma unroll
  for (int kc = 0; kc < 4; ++kc) {
    Bh[kc] = *reinterpret_cast<const i32x4*>(bhp + kc * 64);
    Bl[kc] = *reinterpret_cast<const i32x4*>(blp + kc * 64);
  }

  // zero step-0 spike buffer (this block's columns), then global barrier
  if (on == 0)
    __hip_atomic_store(pk + ob * PKROW + blk, 0u, __ATOMIC_RELAXED,
                       __HIP_MEMORY_SCOPE_AGENT);
  gbar(cnt, NBLK);

  for (int s = 0; s < STEPS; ++s) {
    // ---- load this wave's spike bit-words (coherent IC reads) ----
    unsigned sb[4][4];
    const unsigned* ps = pk + (size_t)s * PKSTEP;
#pragma unroll
    for (int mt = 0; mt < 4; ++mt) {
      const unsigned* pr = ps + (mt * 16 + l15) * PKROW + w * 16 + lhi;
#pragma unroll
      for (int kc = 0; kc < 4; ++kc)
        sb[mt][kc] = __hip_atomic_load(pr + 4 * kc, __ATOMIC_RELAXED,
                                       __HIP_MEMORY_SCOPE_AGENT);
    }

    // ---- MFMA: expand bits to i8 A-fragments in-register ----
    i32x4 acch[4], accl[4];
#pragma unroll
    for (int mt = 0; mt < 4; ++mt) {
      acch[mt] = (i32x4){0, 0, 0, 0};
      accl[mt] = (i32x4){0, 0, 0, 0};
    }
#pragma unroll
    for (int mt = 0; mt < 4; ++mt)
#pragma unroll
      for (int kc = 0; kc < 4; ++kc) {
        i32x4 a = expand16(sb[mt][kc]);
        acch[mt] = __builtin_amdgcn_mfma_i32_16x16x64_i8(a, Bh[kc], acch[mt], 0, 0, 0);
        accl[mt] = __builtin_amdgcn_mfma_i32_16x16x64_i8(a, Bl[kc], accl[mt], 0, 0, 0);
      }

    // ---- exact plane combine, dump to LDS ----
#pragma unroll
    for (int mt = 0; mt < 4; ++mt) {
      i32x4 vi;
#pragma unroll
      for (int r = 0; r < 4; ++r) vi[r] = (acch[mt][r] << 8) + accl[mt][r];
      red[w][mt][lane] = vi;
    }
    __syncthreads();

    // ---- LIF update on register state ----
    {
      const int mto = ob >> 4;
      const int li  = ((ob >> 2) & 3) * 16 + on;  // C/D: col=lane&15,row=(lane>>4)*4+r
      const int r   = ob & 3;
      int sum = 0;
#pragma unroll
      for (int ww = 0; ww < 16; ++ww) sum += red[ww][mto][li][r];

      float rec = QLO_C * (float)sum;
      float is = isyn * SYNDEC + iin + rec;
      float vv = v + (0.1f * (is - v)) / 20.0f;       // match ref op order
      bool sp = (vv >= 20.0f);
      v = sp ? 0.0f : vv;
      isyn = is;

      unsigned long long m = __ballot(sp);
      if ((lane & 15) == 0) {
        int j = lane >> 4;   // halfword j = rows w*4 + j
        unsigned hw = (unsigned)((m >> (16 * j)) & 0xFFFFull);
        __hip_atomic_store(pk + (size_t)(s + 1) * PKSTEP + (w * 4 + j) * PKROW + blk,
                           hw, __ATOMIC_RELAXED, __HIP_MEMORY_SCOPE_AGENT);
      }
    }
    if (s < STEPS - 1) gbar(cnt, (unsigned)(s + 2) * NBLK);
  }
}

// ---------------- epilogue from packed spike history -----------------------

__global__ __launch_bounds__(256) void final_pk(const unsigned* __restrict__ pk,
                                                const float* __restrict__ Wout,
                                                float* __restrict__ out) {
  int b = blockIdx.x, t = threadIdx.x;
  int lane = t & 63, wid = t >> 6;
  float wv[16];
#pragma unroll
  for (int i = 0; i < 16; ++i) wv[i] = Wout[t * 16 + i];
  __shared__ float red4[4];
  float acc = 0.0f;
  for (int s = 1; s <= STEPS; ++s) {
    unsigned h = __hip_atomic_load(pk + (size_t)s * PKSTEP + b * PKROW + t,
                                   __ATOMIC_RELAXED, __HIP_MEMORY_SCOPE_AGENT);
    float m = 0.0f;
#pragma unroll
    for (int i = 0; i < 16; ++i)
      if ((h >> i) & 1u) m += wv[i];
#pragma unroll
    for (int off = 32; off > 0; off >>= 1) m += __shfl_down(m, off);
    if (lane == 0) red4[wid] = m;
    __syncthreads();
    if (t == 0) acc += tanhf(red4[0] + red4[1] + red4[2] + red4[3]);
    __syncthreads();
  }
  if (t == 0) out[b] = acc * (1.0f / (float)STEPS);
}

// ================= round-6 proven fallback path ============================

__global__ __launch_bounds__(256) void init_kernel(const float* __restrict__ obs,
                                                   const float* __restrict__ Win,
                                                   float* __restrict__ iin,
                                                   float* __restrict__ v,
                                                   float* __restrict__ isyn,
                                                   signed char* __restrict__ S8a) {
  int idx = blockIdx.x * 256 + threadIdx.x;
  int b = idx >> 12, n = idx & (NN - 1);
  float o0 = obs[b * 2 + 0], o1 = obs[b * 2 + 1];
  float w0 = Win[n * 2 + 0], w1 = Win[n * 2 + 1];
  iin[idx]  = 5.0f * (o0 * w0 + o1 * w1);
  v[idx]    = 0.0f;
  isyn[idx] = 0.0f;
  S8a[idx]  = 0;
}

__global__ __launch_bounds__(1024) void step_kernel(
    const signed char* __restrict__ S8in,
    signed char* __restrict__ S8out,
    const signed char* __restrict__ Ph,
    const signed char* __restrict__ Pl,
    const float* __restrict__ iin,
    float* __restrict__ v,
    float* __restrict__ isyn,
    const float* __restrict__ Wout,
    float* __restrict__ mpart,
    int s) {
  const int blk = blockIdx.x;
  const int n0  = blk * NPB;
  const int t   = threadIdx.x;
  const int lane = t & 63;
  const int w    = t >> 6;
  const int l15  = lane & 15, lhi = lane >> 4;

  __shared__ i32x4 red[16][4][64];

  const int kbase = w * 256 + lhi * 16;
  const signed char* ap  = S8in + (size_t)l15 * NN + kbase;
  const signed char* bhp = Ph   + (size_t)(n0 + l15) * NN + kbase;
  const signed char* blp = Pl   + (size_t)(n0 + l15) * NN + kbase;

  i32x4 acch[4], accl[4];
#pragma unroll
  for (int mt = 0; mt < 4; ++mt) {
    acch[mt] = (i32x4){0, 0, 0, 0};
    accl[mt] = (i32x4){0, 0, 0, 0};
  }
#pragma unroll
  for (int kc = 0; kc < 4; ++kc) {
    i32x4 bh = *reinterpret_cast<const i32x4*>(bhp + kc * 64);
    i32x4 bl = *reinterpret_cast<const i32x4*>(blp + kc * 64);
#pragma unroll
    for (int mt = 0; mt < 4; ++mt) {
      i32x4 a = *reinterpret_cast<const i32x4*>(ap + kc * 64 + (size_t)mt * 16 * NN);
      acch[mt] = __builtin_amdgcn_mfma_i32_16x16x64_i8(a, bh, acch[mt], 0, 0, 0);
      accl[mt] = __builtin_amdgcn_mfma_i32_16x16x64_i8(a, bl, accl[mt], 0, 0, 0);
    }
  }
#pragma unroll
  for (int mt = 0; mt < 4; ++mt) {
    i32x4 vi;
#pragma unroll
    for (int r = 0; r < 4; ++r) vi[r] = (acch[mt][r] << 8) + accl[mt][r];
    red[w][mt][lane] = vi;
  }
  __syncthreads();
  {
    const int b  = t >> 4;
    const int nl = t & 15;
    const int mt = b >> 4;
    const int li = ((b >> 2) & 3) * 16 + nl;
    const int r  = b & 3;
    int sum = 0;
#pragma unroll
    for (int ww = 0; ww < 16; ++ww) sum += red[ww][mt][li][r];

    const size_t e = (size_t)b * NN + n0 + nl;
    float rec = QLO_C * (float)sum;
    float vold = v[e];
    float is = isyn[e] * SYNDEC + iin[e] + rec;
    float vv = vold + (0.1f * (is - vold)) / 20.0f;
    bool sp = (vv >= 20.0f);
    v[e]     = sp ? 0.0f : vv;
    isyn[e]  = is;
    S8out[e] = sp ? 1 : 0;

    float mot = sp ? Wout[n0 + nl] : 0.0f;
#pragma unroll
    for (int off = 1; off < 16; off <<= 1) mot += __shfl_xor(mot, off);
    if (nl == 0) mpart[((size_t)s * BB + b) * NBLK + blk] = mot;
  }
}

__global__ __launch_bounds__(256) void final_mpart(const float* __restrict__ mpart,
                                                   float* __restrict__ out) {
  int b = blockIdx.x;
  int t = threadIdx.x;
  int lane = t & 63, wid = t >> 6;
  __shared__ float red[4];
  float acc = 0.0f;
  for (int s = 0; s < STEPS; ++s) {
    float x = mpart[((size_t)s * BB + b) * NBLK + t];
#pragma unroll
    for (int off = 32; off > 0; off >>= 1) x += __shfl_down(x, off);
    if (lane == 0) red[wid] = x;
    __syncthreads();
    if (t == 0) acc += tanhf(red[0] + red[1] + red[2] + red[3]);
    __syncthreads();
  }
  if (t == 0) out[b] = acc * (1.0f / (float)STEPS);
}

// ---------------------------------------------------------------------------

extern "C" void kernel_launch(void* const* d_in, const int* in_sizes, int n_in,
                              void* d_out, int out_size, void* d_ws, size_t ws_size,
                              hipStream_t stream) {
  const float* obs  = (const float*)d_in[0];   // [64,2]
  const float* Win  = (const float*)d_in[1];   // [4096,2]
  const float* Wrec = (const float*)d_in[2];   // [4096,4096]
  const float* Wout = (const float*)d_in[3];   // [1,4096]

  char* ws = (char*)d_ws;
  size_t off = 0;
  auto alloc = [&](size_t bytes) -> void* {
    void* p = ws + off;
    off += (bytes + 255) & ~(size_t)255;
    return p;
  };
  signed char* Ph  = (signed char*)alloc((size_t)NN * NN);            // 16 MB
  signed char* Pl  = (signed char*)alloc((size_t)NN * NN);            // 16 MB
  unsigned* pk     = (unsigned*)alloc((size_t)(STEPS + 1) * PKSTEP * 4);  // 3.3 MB
  unsigned* cnt    = (unsigned*)alloc(256);
  // fallback-path buffers
  float* iin       = (float*)alloc((size_t)BB * NN * 4);
  float* v         = (float*)alloc((size_t)BB * NN * 4);
  float* isyn      = (float*)alloc((size_t)BB * NN * 4);
  signed char* S8a = (signed char*)alloc((size_t)BB * NN);
  signed char* S8b = (signed char*)alloc((size_t)BB * NN);
  float* mpart     = (float*)alloc((size_t)STEPS * BB * NBLK * 4);

  quant_kernel<<<(NN * NN) / 1024, 256, 0, stream>>>(Wrec, Ph, Pl, cnt);

  void* args[] = {&Ph, &Pl, (void*)&obs, (void*)&Win, &pk, &cnt};
  hipError_t cerr = hipLaunchCooperativeKernel((void*)brain2, dim3(NBLK),
                                               dim3(1024), args, 0, stream);
  if (cerr == hipSuccess) {
    final_pk<<<BB, 256, 0, stream>>>(pk, Wout, (float*)d_out);
  } else {
    // round-6 proven fallback
    init_kernel<<<(BB * NN) / 256, 256, 0, stream>>>(obs, Win, iin, v, isyn, S8a);
    for (int s = 0; s < STEPS; ++s) {
      const signed char* sin = (s & 1) ? S8b : S8a;
      signed char* sout      = (s & 1) ? S8a : S8b;
      step_kernel<<<NBLK, 1024, 0, stream>>>(sin, sout, Ph, Pl, iin, v, isyn,
                                             Wout, mpart, s);
    }
    final_mpart<<<BB, 256, 0, stream>>>(mpart, (float*)d_out);
  }
}

// Round 9
// 630.401 us; speedup vs baseline: 1.5163x; 1.5163x over previous
//
#include <hip/hip_runtime.h>
#include <math.h>

// SpikingPendulumBrain — single persistent kernel.
//  * W_rec as two int8 planes (exact int32 MFMA; validated absmax 0.0 in
//    rounds 2/4/5/6/8). Each wave holds its B fragments in 32 VGPRs for the
//    whole 50 steps -> zero per-step weight traffic (FETCH 29MB, round 8).
//  * v/isyn/iin in registers. Only spikes cross blocks: bit-packed, one
//    64KB buffer per step, accessed exclusively via relaxed agent-scope
//    atomics (bypass non-coherent per-XCD L2s + stale poison lines).
//  * Barrier: distributed store/poll flags. Round-8's RELEASE fetch_add
//    barrier cost ~13us/step (buffer_wbl2 L2-writeback per release + RMW
//    serialization). Here: vmcnt(0) drain + __syncthreads + relaxed flag
//    STORE per block; readers poll 256 flags in parallel (relaxed loads,
//    s_sleep). pk stores are acked at the coherence point before the flag
//    store issues -> publication is ordered without any release fence.
//  * k-map permuted (A/B consistently) so spike words are lane-contiguous:
//    8x 64-bit atomic loads per wave instead of 16 scalar.
//  * Fallback: round-6 proven multi-launch path if coop launch is rejected.

#define NN 4096
#define BB 64
#define STEPS 50
#define NBLK 256
#define NPB 16
#define PKROW 256                    // dwords per packed row (uint32 per 16 cols)
#define PKSTEP (BB * PKROW)          // dwords per step buffer

typedef __attribute__((ext_vector_type(4))) int i32x4;

static constexpr float WMAX_C = 0.16f;
static constexpr float QHI_C  = WMAX_C / 127.0f;
static constexpr float QLO_C  = QHI_C / 256.0f;
static constexpr float SYNDEC = (float)0.9801986733067553;  // exp(-0.1/5)

// ---------------- one-time prep (re-run every call; ws is re-poisoned) -----

__global__ __launch_bounds__(256) void quant_kernel(const float* __restrict__ W,
                                                    signed char* __restrict__ Ph,
                                                    signed char* __restrict__ Pl,
                                                    unsigned* __restrict__ flags) {
  int idx = blockIdx.x * 256 + threadIdx.x;
  float4 w4 = reinterpret_cast<const float4*>(W)[idx];
  float w[4] = {w4.x, w4.y, w4.z, w4.w};
  signed char hi[4], lo[4];
#pragma unroll
  for (int i = 0; i < 4; i++) {
    float h = rintf(w[i] * (1.0f / QHI_C));
    h = fminf(127.0f, fmaxf(-127.0f, h));
    float r = fmaf(h, -QHI_C, w[i]);
    float l = rintf(r * (1.0f / QLO_C));
    l = fminf(127.0f, fmaxf(-127.0f, l));
    hi[i] = (signed char)(int)h;
    lo[i] = (signed char)(int)l;
  }
  reinterpret_cast<char4*>(Ph)[idx] = make_char4(hi[0], hi[1], hi[2], hi[3]);
  reinterpret_cast<char4*>(Pl)[idx] = make_char4(lo[0], lo[1], lo[2], lo[3]);
  if (blockIdx.x == 0 && threadIdx.x < NBLK) flags[threadIdx.x] = 0;
}

// ---------------- helpers ---------------------------------------------------

__device__ __forceinline__ i32x4 expand16(unsigned h) {
  // 16 bits -> 16 bytes (0/1): nibble q -> dword q via bit-spread multiply
  i32x4 a;
#pragma unroll
  for (int q = 0; q < 4; ++q) {
    unsigned nib = (h >> (4 * q)) & 0xFu;
    a[q] = (int)((nib * 0x00204081u) & 0x01010101u);
  }
  return a;
}

// ---------------- persistent brain kernel ----------------------------------
// 256 blocks x 1024 threads (16 waves, 1 block/CU). Block owns neurons
// [blk*16, +16), all 64 batch rows, full K. Wave w owns K-slice [w*256,+256)
// with its B fragments HELD IN REGISTERS across all steps. Spikes cross
// blocks as packed bits: pk[s][row][col16] uint32 (low 16 bits).
// Permuted k-map: A word for (kc,lhi) = pk word w*16 + lhi*4 + kc; B
// fragment (kc,lhi) reads slice bytes lhi*64 + kc*16 (+i). Both sides carry
// k = w*256 + lhi*64 + kc*16 + i -> contraction unchanged.

__global__ __launch_bounds__(1024, 1) void brain2(
    const signed char* __restrict__ Ph,
    const signed char* __restrict__ Pl,
    const float* __restrict__ obs,
    const float* __restrict__ Win,
    unsigned* __restrict__ pk,
    unsigned* __restrict__ flags) {
  const int blk = blockIdx.x;
  const int n0  = blk * NPB;
  const int t   = threadIdx.x;
  const int lane = t & 63;
  const int w    = t >> 6;
  const int l15  = lane & 15, lhi = lane >> 4;
  const int ob   = t >> 4;          // owned batch row
  const int on   = t & 15;          // owned neuron (within block)

  __shared__ i32x4 red[16][4][64];  // 64KB cross-wave int32 partials

  // per-thread state in registers
  float iin = 5.0f * (obs[ob * 2 + 0] * Win[(n0 + on) * 2 + 0] +
                      obs[ob * 2 + 1] * Win[(n0 + on) * 2 + 1]);
  float v = 0.0f, isyn = 0.0f;

  // B fragments held for the whole kernel (permuted k-map: lhi*64 + kc*16)
  const signed char* bhp = Ph + (size_t)(n0 + l15) * NN + w * 256 + lhi * 64;
  const signed char* blp = Pl + (size_t)(n0 + l15) * NN + w * 256 + lhi * 64;
  i32x4 Bh[4], Bl[4];
#pragma unroll
  for (int kc = 0; kc < 4; ++kc) {
    Bh[kc] = *reinterpret_cast<const i32x4*>(bhp + kc * 16);
    Bl[kc] = *reinterpret_cast<const i32x4*>(blp + kc * 16);
  }

  // zero step-0 spike buffer (this block's columns), publish flag=1
  if (on == 0)
    __hip_atomic_store(pk + ob * PKROW + blk, 0u, __ATOMIC_RELAXED,
                       __HIP_MEMORY_SCOPE_AGENT);
  asm volatile("s_waitcnt vmcnt(0)" ::: "memory");
  __syncthreads();
  if (t == 0)
    __hip_atomic_store(flags + blk, 1u, __ATOMIC_RELAXED,
                       __HIP_MEMORY_SCOPE_AGENT);

  for (int s = 0; s < STEPS; ++s) {
    // ---- wait: all 256 blocks published phase s+1 ----
    if (t < NBLK) {
      while (__hip_atomic_load(flags + t, __ATOMIC_RELAXED,
                               __HIP_MEMORY_SCOPE_AGENT) < (unsigned)(s + 1))
        __builtin_amdgcn_s_sleep(1);
    }
    __syncthreads();

    // ---- load this wave's spike bit-words (coherent, 64-bit pairs) ----
    unsigned sb[4][4];
    const unsigned* ps = pk + (size_t)s * PKSTEP;
#pragma unroll
    for (int mt = 0; mt < 4; ++mt) {
      const unsigned* pr = ps + (mt * 16 + l15) * PKROW + w * 16 + lhi * 4;
      unsigned long long u0 = __hip_atomic_load(
          reinterpret_cast<const unsigned long long*>(pr), __ATOMIC_RELAXED,
          __HIP_MEMORY_SCOPE_AGENT);
      unsigned long long u1 = __hip_atomic_load(
          reinterpret_cast<const unsigned long long*>(pr + 2), __ATOMIC_RELAXED,
          __HIP_MEMORY_SCOPE_AGENT);
      sb[mt][0] = (unsigned)u0;
      sb[mt][1] = (unsigned)(u0 >> 32);
      sb[mt][2] = (unsigned)u1;
      sb[mt][3] = (unsigned)(u1 >> 32);
    }

    // ---- MFMA: expand bits to i8 A-fragments in-register ----
    i32x4 acch[4], accl[4];
#pragma unroll
    for (int mt = 0; mt < 4; ++mt) {
      acch[mt] = (i32x4){0, 0, 0, 0};
      accl[mt] = (i32x4){0, 0, 0, 0};
    }
#pragma unroll
    for (int mt = 0; mt < 4; ++mt)
#pragma unroll
      for (int kc = 0; kc < 4; ++kc) {
        i32x4 a = expand16(sb[mt][kc]);
        acch[mt] = __builtin_amdgcn_mfma_i32_16x16x64_i8(a, Bh[kc], acch[mt], 0, 0, 0);
        accl[mt] = __builtin_amdgcn_mfma_i32_16x16x64_i8(a, Bl[kc], accl[mt], 0, 0, 0);
      }

    // ---- exact plane combine, dump to LDS ----
#pragma unroll
    for (int mt = 0; mt < 4; ++mt) {
      i32x4 vi;
#pragma unroll
      for (int r = 0; r < 4; ++r) vi[r] = (acch[mt][r] << 8) + accl[mt][r];
      red[w][mt][lane] = vi;
    }
    __syncthreads();

    // ---- LIF update on register state ----
    {
      const int mto = ob >> 4;
      const int li  = ((ob >> 2) & 3) * 16 + on;  // C/D: col=lane&15,row=(lane>>4)*4+r
      const int r   = ob & 3;
      int sum = 0;
#pragma unroll
      for (int ww = 0; ww < 16; ++ww) sum += red[ww][mto][li][r];

      float rec = QLO_C * (float)sum;
      float is = isyn * SYNDEC + iin + rec;
      float vv = v + (0.1f * (is - v)) / 20.0f;       // match ref op order
      bool sp = (vv >= 20.0f);
      v = sp ? 0.0f : vv;
      isyn = is;

      unsigned long long m = __ballot(sp);
      if ((lane & 15) == 0) {
        int j = lane >> 4;   // halfword j = rows w*4 + j
        unsigned hw = (unsigned)((m >> (16 * j)) & 0xFFFFull);
        __hip_atomic_store(pk + (size_t)(s + 1) * PKSTEP + (w * 4 + j) * PKROW + blk,
                           hw, __ATOMIC_RELAXED, __HIP_MEMORY_SCOPE_AGENT);
      }
    }
    // ---- publish: drain pk stores, then flag = s+2 (no release fence) ----
    if (s < STEPS - 1) {
      asm volatile("s_waitcnt vmcnt(0)" ::: "memory");
      __syncthreads();   // LDS red also safe for reuse next iter
      if (t == 0)
        __hip_atomic_store(flags + blk, (unsigned)(s + 2), __ATOMIC_RELAXED,
                           __HIP_MEMORY_SCOPE_AGENT);
    }
  }
}

// ---------------- epilogue from packed spike history -----------------------

__global__ __launch_bounds__(256) void final_pk(const unsigned* __restrict__ pk,
                                                const float* __restrict__ Wout,
                                                float* __restrict__ out) {
  int b = blockIdx.x, t = threadIdx.x;
  int lane = t & 63, wid = t >> 6;
  float wv[16];
#pragma unroll
  for (int i = 0; i < 16; ++i) wv[i] = Wout[t * 16 + i];
  __shared__ float red4[4];
  float acc = 0.0f;
  for (int s = 1; s <= STEPS; ++s) {
    unsigned h = __hip_atomic_load(pk + (size_t)s * PKSTEP + b * PKROW + t,
                                   __ATOMIC_RELAXED, __HIP_MEMORY_SCOPE_AGENT);
    float m = 0.0f;
#pragma unroll
    for (int i = 0; i < 16; ++i)
      if ((h >> i) & 1u) m += wv[i];
#pragma unroll
    for (int off = 32; off > 0; off >>= 1) m += __shfl_down(m, off);
    if (lane == 0) red4[wid] = m;
    __syncthreads();
    if (t == 0) acc += tanhf(red4[0] + red4[1] + red4[2] + red4[3]);
    __syncthreads();
  }
  if (t == 0) out[b] = acc * (1.0f / (float)STEPS);
}

// ================= round-6 proven fallback path ============================

__global__ __launch_bounds__(256) void init_kernel(const float* __restrict__ obs,
                                                   const float* __restrict__ Win,
                                                   float* __restrict__ iin,
                                                   float* __restrict__ v,
                                                   float* __restrict__ isyn,
                                                   signed char* __restrict__ S8a) {
  int idx = blockIdx.x * 256 + threadIdx.x;
  int b = idx >> 12, n = idx & (NN - 1);
  float o0 = obs[b * 2 + 0], o1 = obs[b * 2 + 1];
  float w0 = Win[n * 2 + 0], w1 = Win[n * 2 + 1];
  iin[idx]  = 5.0f * (o0 * w0 + o1 * w1);
  v[idx]    = 0.0f;
  isyn[idx] = 0.0f;
  S8a[idx]  = 0;
}

__global__ __launch_bounds__(1024) void step_kernel(
    const signed char* __restrict__ S8in,
    signed char* __restrict__ S8out,
    const signed char* __restrict__ Ph,
    const signed char* __restrict__ Pl,
    const float* __restrict__ iin,
    float* __restrict__ v,
    float* __restrict__ isyn,
    const float* __restrict__ Wout,
    float* __restrict__ mpart,
    int s) {
  const int blk = blockIdx.x;
  const int n0  = blk * NPB;
  const int t   = threadIdx.x;
  const int lane = t & 63;
  const int w    = t >> 6;
  const int l15  = lane & 15, lhi = lane >> 4;

  __shared__ i32x4 red[16][4][64];

  const int kbase = w * 256 + lhi * 16;
  const signed char* ap  = S8in + (size_t)l15 * NN + kbase;
  const signed char* bhp = Ph   + (size_t)(n0 + l15) * NN + kbase;
  const signed char* blp = Pl   + (size_t)(n0 + l15) * NN + kbase;

  i32x4 acch[4], accl[4];
#pragma unroll
  for (int mt = 0; mt < 4; ++mt) {
    acch[mt] = (i32x4){0, 0, 0, 0};
    accl[mt] = (i32x4){0, 0, 0, 0};
  }
#pragma unroll
  for (int kc = 0; kc < 4; ++kc) {
    i32x4 bh = *reinterpret_cast<const i32x4*>(bhp + kc * 64);
    i32x4 bl = *reinterpret_cast<const i32x4*>(blp + kc * 64);
#pragma unroll
    for (int mt = 0; mt < 4; ++mt) {
      i32x4 a = *reinterpret_cast<const i32x4*>(ap + kc * 64 + (size_t)mt * 16 * NN);
      acch[mt] = __builtin_amdgcn_mfma_i32_16x16x64_i8(a, bh, acch[mt], 0, 0, 0);
      accl[mt] = __builtin_amdgcn_mfma_i32_16x16x64_i8(a, bl, accl[mt], 0, 0, 0);
    }
  }
#pragma unroll
  for (int mt = 0; mt < 4; ++mt) {
    i32x4 vi;
#pragma unroll
    for (int r = 0; r < 4; ++r) vi[r] = (acch[mt][r] << 8) + accl[mt][r];
    red[w][mt][lane] = vi;
  }
  __syncthreads();
  {
    const int b  = t >> 4;
    const int nl = t & 15;
    const int mt = b >> 4;
    const int li = ((b >> 2) & 3) * 16 + nl;
    const int r  = b & 3;
    int sum = 0;
#pragma unroll
    for (int ww = 0; ww < 16; ++ww) sum += red[ww][mt][li][r];

    const size_t e = (size_t)b * NN + n0 + nl;
    float rec = QLO_C * (float)sum;
    float vold = v[e];
    float is = isyn[e] * SYNDEC + iin[e] + rec;
    float vv = vold + (0.1f * (is - vold)) / 20.0f;
    bool sp = (vv >= 20.0f);
    v[e]     = sp ? 0.0f : vv;
    isyn[e]  = is;
    S8out[e] = sp ? 1 : 0;

    float mot = sp ? Wout[n0 + nl] : 0.0f;
#pragma unroll
    for (int off = 1; off < 16; off <<= 1) mot += __shfl_xor(mot, off);
    if (nl == 0) mpart[((size_t)s * BB + b) * NBLK + blk] = mot;
  }
}

__global__ __launch_bounds__(256) void final_mpart(const float* __restrict__ mpart,
                                                   float* __restrict__ out) {
  int b = blockIdx.x;
  int t = threadIdx.x;
  int lane = t & 63, wid = t >> 6;
  __shared__ float red[4];
  float acc = 0.0f;
  for (int s = 0; s < STEPS; ++s) {
    float x = mpart[((size_t)s * BB + b) * NBLK + t];
#pragma unroll
    for (int off = 32; off > 0; off >>= 1) x += __shfl_down(x, off);
    if (lane == 0) red[wid] = x;
    __syncthreads();
    if (t == 0) acc += tanhf(red[0] + red[1] + red[2] + red[3]);
    __syncthreads();
  }
  if (t == 0) out[b] = acc * (1.0f / (float)STEPS);
}

// ---------------------------------------------------------------------------

extern "C" void kernel_launch(void* const* d_in, const int* in_sizes, int n_in,
                              void* d_out, int out_size, void* d_ws, size_t ws_size,
                              hipStream_t stream) {
  const float* obs  = (const float*)d_in[0];   // [64,2]
  const float* Win  = (const float*)d_in[1];   // [4096,2]
  const float* Wrec = (const float*)d_in[2];   // [4096,4096]
  const float* Wout = (const float*)d_in[3];   // [1,4096]

  char* ws = (char*)d_ws;
  size_t off = 0;
  auto alloc = [&](size_t bytes) -> void* {
    void* p = ws + off;
    off += (bytes + 255) & ~(size_t)255;
    return p;
  };
  signed char* Ph  = (signed char*)alloc((size_t)NN * NN);            // 16 MB
  signed char* Pl  = (signed char*)alloc((size_t)NN * NN);            // 16 MB
  unsigned* pk     = (unsigned*)alloc((size_t)(STEPS + 1) * PKSTEP * 4);  // 3.3 MB
  unsigned* flags  = (unsigned*)alloc(NBLK * 4);
  // fallback-path buffers
  float* iin       = (float*)alloc((size_t)BB * NN * 4);
  float* v         = (float*)alloc((size_t)BB * NN * 4);
  float* isyn      = (float*)alloc((size_t)BB * NN * 4);
  signed char* S8a = (signed char*)alloc((size_t)BB * NN);
  signed char* S8b = (signed char*)alloc((size_t)BB * NN);
  float* mpart     = (float*)alloc((size_t)STEPS * BB * NBLK * 4);

  quant_kernel<<<(NN * NN) / 1024, 256, 0, stream>>>(Wrec, Ph, Pl, flags);

  void* args[] = {&Ph, &Pl, (void*)&obs, (void*)&Win, &pk, &flags};
  hipError_t cerr = hipLaunchCooperativeKernel((void*)brain2, dim3(NBLK),
                                               dim3(1024), args, 0, stream);
  if (cerr == hipSuccess) {
    final_pk<<<BB, 256, 0, stream>>>(pk, Wout, (float*)d_out);
  } else {
    // round-6 proven fallback
    init_kernel<<<(BB * NN) / 256, 256, 0, stream>>>(obs, Win, iin, v, isyn, S8a);
    for (int s = 0; s < STEPS; ++s) {
      const signed char* sin = (s & 1) ? S8b : S8a;
      signed char* sout      = (s & 1) ? S8a : S8b;
      step_kernel<<<NBLK, 1024, 0, stream>>>(sin, sout, Ph, Pl, iin, v, isyn,
                                             Wout, mpart, s);
    }
    final_mpart<<<BB, 256, 0, stream>>>(mpart, (float*)d_out);
  }
}

// Round 10
// 574.449 us; speedup vs baseline: 1.6640x; 1.0974x over previous
//
#include <hip/hip_runtime.h>
#include <math.h>

// SpikingPendulumBrain — single persistent kernel, data-sentinel sync.
//  * W_rec as two int8 planes (exact int32 MFMA; absmax 0.0 rounds 2/4/5/6/8/9).
//    Each wave holds its B fragments in 32 VGPRs all 50 steps (FETCH ~30MB).
//  * v/isyn/iin in registers. Spikes cross blocks bit-packed: pk[s][row][col]
//    u32, low 16 bits = spikes, HIGH 16 BITS ALWAYS 0 when written.
//  * SYNC = DATA SENTINEL: quant pre-fills pk[1..50] with 0xAAAA0000 (high
//    bits set) and zeroes pk[0]. Consumers poll the needed words until the
//    high half clears -> store visibility IS the barrier. No flags, no
//    vmcnt drain, no grid-wide wait; each wave waits only on its own 16
//    producer columns. (Round 9's flag barrier cost ~6us/step in IC
//    round-trips; this removes the indirection.)
//  * All pk accesses agent-scope atomics (bypass non-coherent per-XCD L2s;
//    consumer L2 would otherwise cache the sentinel and spin forever).
//  * Fallback: round-6 proven multi-launch path if coop launch is rejected.

#define NN 4096
#define BB 64
#define STEPS 50
#define NBLK 256
#define NPB 16
#define PKROW 256                    // dwords per packed row (u32 per 16 cols)
#define PKSTEP (BB * PKROW)          // dwords per step buffer (64KB)

typedef __attribute__((ext_vector_type(4))) int i32x4;

static constexpr float WMAX_C = 0.16f;
static constexpr float QHI_C  = WMAX_C / 127.0f;
static constexpr float QLO_C  = QHI_C / 256.0f;
static constexpr float SYNDEC = (float)0.9801986733067553;  // exp(-0.1/5)
#define HIMASK 0xFFFF0000FFFF0000ull

// ---------------- one-time prep (re-run every call; ws is re-poisoned) -----

__global__ __launch_bounds__(256) void quant_kernel(const float* __restrict__ W,
                                                    signed char* __restrict__ Ph,
                                                    signed char* __restrict__ Pl,
                                                    unsigned* __restrict__ pk) {
  int idx = blockIdx.x * 256 + threadIdx.x;
  float4 w4 = reinterpret_cast<const float4*>(W)[idx];
  float w[4] = {w4.x, w4.y, w4.z, w4.w};
  signed char hi[4], lo[4];
#pragma unroll
  for (int i = 0; i < 4; i++) {
    float h = rintf(w[i] * (1.0f / QHI_C));
    h = fminf(127.0f, fmaxf(-127.0f, h));
    float r = fmaf(h, -QHI_C, w[i]);
    float l = rintf(r * (1.0f / QLO_C));
    l = fminf(127.0f, fmaxf(-127.0f, l));
    hi[i] = (signed char)(int)h;
    lo[i] = (signed char)(int)l;
  }
  reinterpret_cast<char4*>(Ph)[idx] = make_char4(hi[0], hi[1], hi[2], hi[3]);
  reinterpret_cast<char4*>(Pl)[idx] = make_char4(lo[0], lo[1], lo[2], lo[3]);
  // deterministic pk init: step 0 = all-zero spikes, steps 1..50 = sentinel.
  // Plain stores: kernel-boundary flush/inv makes them coherent for brain2.
  if (idx < (STEPS + 1) * PKSTEP)
    pk[idx] = (idx < PKSTEP) ? 0u : 0xAAAA0000u;
}

// ---------------- helpers ---------------------------------------------------

__device__ __forceinline__ i32x4 expand16(unsigned h) {
  // 16 bits -> 16 bytes (0/1): nibble q -> dword q via bit-spread multiply
  i32x4 a;
#pragma unroll
  for (int q = 0; q < 4; ++q) {
    unsigned nib = (h >> (4 * q)) & 0xFu;
    a[q] = (int)((nib * 0x00204081u) & 0x01010101u);
  }
  return a;
}

__device__ __forceinline__ unsigned long long poll8(const unsigned* p) {
  unsigned long long u = __hip_atomic_load(
      reinterpret_cast<const unsigned long long*>(p), __ATOMIC_RELAXED,
      __HIP_MEMORY_SCOPE_AGENT);
  while (u & HIMASK) {
    __builtin_amdgcn_s_sleep(1);
    u = __hip_atomic_load(reinterpret_cast<const unsigned long long*>(p),
                          __ATOMIC_RELAXED, __HIP_MEMORY_SCOPE_AGENT);
  }
  return u;
}

// ---------------- persistent brain kernel ----------------------------------
// 256 blocks x 1024 threads (16 waves, 1 block/CU). Block owns neurons
// [blk*16, +16), all 64 batch rows, full K. Wave w owns K-slice [w*256,+256)
// with B fragments in registers. Permuted k-map (A/B consistent, validated
// round 9): A word for (kc,lhi) = pk col w*16+lhi*4+kc; B fragment (kc,lhi)
// = slice bytes lhi*64 + kc*16.

__global__ __launch_bounds__(1024, 1) void brain2(
    const signed char* __restrict__ Ph,
    const signed char* __restrict__ Pl,
    const float* __restrict__ obs,
    const float* __restrict__ Win,
    unsigned* __restrict__ pk) {
  const int blk = blockIdx.x;
  const int n0  = blk * NPB;
  const int t   = threadIdx.x;
  const int lane = t & 63;
  const int w    = t >> 6;
  const int l15  = lane & 15, lhi = lane >> 4;
  const int ob   = t >> 4;          // owned batch row
  const int on   = t & 15;          // owned neuron (within block)

  __shared__ i32x4 red[16][4][64];  // 64KB cross-wave int32 partials

  float iin = 5.0f * (obs[ob * 2 + 0] * Win[(n0 + on) * 2 + 0] +
                      obs[ob * 2 + 1] * Win[(n0 + on) * 2 + 1]);
  float v = 0.0f, isyn = 0.0f;

  // B fragments held for the whole kernel (permuted k-map: lhi*64 + kc*16)
  const signed char* bhp = Ph + (size_t)(n0 + l15) * NN + w * 256 + lhi * 64;
  const signed char* blp = Pl + (size_t)(n0 + l15) * NN + w * 256 + lhi * 64;
  i32x4 Bh[4], Bl[4];
#pragma unroll
  for (int kc = 0; kc < 4; ++kc) {
    Bh[kc] = *reinterpret_cast<const i32x4*>(bhp + kc * 16);
    Bl[kc] = *reinterpret_cast<const i32x4*>(blp + kc * 16);
  }

  for (int s = 0; s < STEPS; ++s) {
    // ---- self-synchronizing spike loads (poll until high halves clear) ----
    unsigned sb[4][4];
    const unsigned* ps = pk + (size_t)s * PKSTEP;
#pragma unroll
    for (int mt = 0; mt < 4; ++mt) {
      const unsigned* pr = ps + (mt * 16 + l15) * PKROW + w * 16 + lhi * 4;
      unsigned long long u0 = poll8(pr);
      unsigned long long u1 = poll8(pr + 2);
      sb[mt][0] = (unsigned)u0;
      sb[mt][1] = (unsigned)(u0 >> 32);
      sb[mt][2] = (unsigned)u1;
      sb[mt][3] = (unsigned)(u1 >> 32);
    }

    // ---- MFMA: expand bits to i8 A-fragments in-register ----
    i32x4 acch[4], accl[4];
#pragma unroll
    for (int mt = 0; mt < 4; ++mt) {
      acch[mt] = (i32x4){0, 0, 0, 0};
      accl[mt] = (i32x4){0, 0, 0, 0};
    }
#pragma unroll
    for (int mt = 0; mt < 4; ++mt)
#pragma unroll
      for (int kc = 0; kc < 4; ++kc) {
        i32x4 a = expand16(sb[mt][kc]);
        acch[mt] = __builtin_amdgcn_mfma_i32_16x16x64_i8(a, Bh[kc], acch[mt], 0, 0, 0);
        accl[mt] = __builtin_amdgcn_mfma_i32_16x16x64_i8(a, Bl[kc], accl[mt], 0, 0, 0);
      }

    // ---- exact plane combine, dump to LDS ----
#pragma unroll
    for (int mt = 0; mt < 4; ++mt) {
      i32x4 vi;
#pragma unroll
      for (int r = 0; r < 4; ++r) vi[r] = (acch[mt][r] << 8) + accl[mt][r];
      red[w][mt][lane] = vi;
    }
    __syncthreads();

    // ---- LIF update on register state; publish spikes for step s+1 ----
    {
      const int mto = ob >> 4;
      const int li  = ((ob >> 2) & 3) * 16 + on;  // C/D: col=lane&15,row=(lane>>4)*4+r
      const int r   = ob & 3;
      int sum = 0;
#pragma unroll
      for (int ww = 0; ww < 16; ++ww) sum += red[ww][mto][li][r];

      float rec = QLO_C * (float)sum;
      float is = isyn * SYNDEC + iin + rec;
      float vv = v + (0.1f * (is - v)) / 20.0f;       // match ref op order
      bool sp = (vv >= 20.0f);
      v = sp ? 0.0f : vv;
      isyn = is;

      unsigned long long m = __ballot(sp);
      if ((lane & 15) == 0) {
        int j = lane >> 4;   // halfword j = row w*4 + j
        unsigned hw = (unsigned)((m >> (16 * j)) & 0xFFFFull);  // high 16 = 0
        __hip_atomic_store(pk + (size_t)(s + 1) * PKSTEP + (w * 4 + j) * PKROW + blk,
                           hw, __ATOMIC_RELAXED, __HIP_MEMORY_SCOPE_AGENT);
      }
    }
    __syncthreads();   // red[] WAR protection for next iteration
  }
}

// ---------------- epilogue from packed spike history -----------------------

__global__ __launch_bounds__(256) void final_pk(const unsigned* __restrict__ pk,
                                                const float* __restrict__ Wout,
                                                float* __restrict__ out) {
  int b = blockIdx.x, t = threadIdx.x;
  int lane = t & 63, wid = t >> 6;
  float wv[16];
#pragma unroll
  for (int i = 0; i < 16; ++i) wv[i] = Wout[t * 16 + i];
  __shared__ float red4[4];
  float acc = 0.0f;
  for (int s = 1; s <= STEPS; ++s) {
    unsigned h = __hip_atomic_load(pk + (size_t)s * PKSTEP + b * PKROW + t,
                                   __ATOMIC_RELAXED, __HIP_MEMORY_SCOPE_AGENT);
    float m = 0.0f;
#pragma unroll
    for (int i = 0; i < 16; ++i)
      if ((h >> i) & 1u) m += wv[i];
#pragma unroll
    for (int off = 32; off > 0; off >>= 1) m += __shfl_down(m, off);
    if (lane == 0) red4[wid] = m;
    __syncthreads();
    if (t == 0) acc += tanhf(red4[0] + red4[1] + red4[2] + red4[3]);
    __syncthreads();
  }
  if (t == 0) out[b] = acc * (1.0f / (float)STEPS);
}

// ================= round-6 proven fallback path ============================

__global__ __launch_bounds__(256) void init_kernel(const float* __restrict__ obs,
                                                   const float* __restrict__ Win,
                                                   float* __restrict__ iin,
                                                   float* __restrict__ v,
                                                   float* __restrict__ isyn,
                                                   signed char* __restrict__ S8a) {
  int idx = blockIdx.x * 256 + threadIdx.x;
  int b = idx >> 12, n = idx & (NN - 1);
  float o0 = obs[b * 2 + 0], o1 = obs[b * 2 + 1];
  float w0 = Win[n * 2 + 0], w1 = Win[n * 2 + 1];
  iin[idx]  = 5.0f * (o0 * w0 + o1 * w1);
  v[idx]    = 0.0f;
  isyn[idx] = 0.0f;
  S8a[idx]  = 0;
}

__global__ __launch_bounds__(1024) void step_kernel(
    const signed char* __restrict__ S8in,
    signed char* __restrict__ S8out,
    const signed char* __restrict__ Ph,
    const signed char* __restrict__ Pl,
    const float* __restrict__ iin,
    float* __restrict__ v,
    float* __restrict__ isyn,
    const float* __restrict__ Wout,
    float* __restrict__ mpart,
    int s) {
  const int blk = blockIdx.x;
  const int n0  = blk * NPB;
  const int t   = threadIdx.x;
  const int lane = t & 63;
  const int w    = t >> 6;
  const int l15  = lane & 15, lhi = lane >> 4;

  __shared__ i32x4 red[16][4][64];

  const int kbase = w * 256 + lhi * 16;
  const signed char* ap  = S8in + (size_t)l15 * NN + kbase;
  const signed char* bhp = Ph   + (size_t)(n0 + l15) * NN + kbase;
  const signed char* blp = Pl   + (size_t)(n0 + l15) * NN + kbase;

  i32x4 acch[4], accl[4];
#pragma unroll
  for (int mt = 0; mt < 4; ++mt) {
    acch[mt] = (i32x4){0, 0, 0, 0};
    accl[mt] = (i32x4){0, 0, 0, 0};
  }
#pragma unroll
  for (int kc = 0; kc < 4; ++kc) {
    i32x4 bh = *reinterpret_cast<const i32x4*>(bhp + kc * 64);
    i32x4 bl = *reinterpret_cast<const i32x4*>(blp + kc * 64);
#pragma unroll
    for (int mt = 0; mt < 4; ++mt) {
      i32x4 a = *reinterpret_cast<const i32x4*>(ap + kc * 64 + (size_t)mt * 16 * NN);
      acch[mt] = __builtin_amdgcn_mfma_i32_16x16x64_i8(a, bh, acch[mt], 0, 0, 0);
      accl[mt] = __builtin_amdgcn_mfma_i32_16x16x64_i8(a, bl, accl[mt], 0, 0, 0);
    }
  }
#pragma unroll
  for (int mt = 0; mt < 4; ++mt) {
    i32x4 vi;
#pragma unroll
    for (int r = 0; r < 4; ++r) vi[r] = (acch[mt][r] << 8) + accl[mt][r];
    red[w][mt][lane] = vi;
  }
  __syncthreads();
  {
    const int b  = t >> 4;
    const int nl = t & 15;
    const int mt = b >> 4;
    const int li = ((b >> 2) & 3) * 16 + nl;
    const int r  = b & 3;
    int sum = 0;
#pragma unroll
    for (int ww = 0; ww < 16; ++ww) sum += red[ww][mt][li][r];

    const size_t e = (size_t)b * NN + n0 + nl;
    float rec = QLO_C * (float)sum;
    float vold = v[e];
    float is = isyn[e] * SYNDEC + iin[e] + rec;
    float vv = vold + (0.1f * (is - vold)) / 20.0f;
    bool sp = (vv >= 20.0f);
    v[e]     = sp ? 0.0f : vv;
    isyn[e]  = is;
    S8out[e] = sp ? 1 : 0;

    float mot = sp ? Wout[n0 + nl] : 0.0f;
#pragma unroll
    for (int off = 1; off < 16; off <<= 1) mot += __shfl_xor(mot, off);
    if (nl == 0) mpart[((size_t)s * BB + b) * NBLK + blk] = mot;
  }
}

__global__ __launch_bounds__(256) void final_mpart(const float* __restrict__ mpart,
                                                   float* __restrict__ out) {
  int b = blockIdx.x;
  int t = threadIdx.x;
  int lane = t & 63, wid = t >> 6;
  __shared__ float red[4];
  float acc = 0.0f;
  for (int s = 0; s < STEPS; ++s) {
    float x = mpart[((size_t)s * BB + b) * NBLK + t];
#pragma unroll
    for (int off = 32; off > 0; off >>= 1) x += __shfl_down(x, off);
    if (lane == 0) red[wid] = x;
    __syncthreads();
    if (t == 0) acc += tanhf(red[0] + red[1] + red[2] + red[3]);
    __syncthreads();
  }
  if (t == 0) out[b] = acc * (1.0f / (float)STEPS);
}

// ---------------------------------------------------------------------------

extern "C" void kernel_launch(void* const* d_in, const int* in_sizes, int n_in,
                              void* d_out, int out_size, void* d_ws, size_t ws_size,
                              hipStream_t stream) {
  const float* obs  = (const float*)d_in[0];   // [64,2]
  const float* Win  = (const float*)d_in[1];   // [4096,2]
  const float* Wrec = (const float*)d_in[2];   // [4096,4096]
  const float* Wout = (const float*)d_in[3];   // [1,4096]

  char* ws = (char*)d_ws;
  size_t off = 0;
  auto alloc = [&](size_t bytes) -> void* {
    void* p = ws + off;
    off += (bytes + 255) & ~(size_t)255;
    return p;
  };
  signed char* Ph  = (signed char*)alloc((size_t)NN * NN);            // 16 MB
  signed char* Pl  = (signed char*)alloc((size_t)NN * NN);            // 16 MB
  unsigned* pk     = (unsigned*)alloc((size_t)(STEPS + 1) * PKSTEP * 4);  // 3.3 MB
  // fallback-path buffers
  float* iin       = (float*)alloc((size_t)BB * NN * 4);
  float* v         = (float*)alloc((size_t)BB * NN * 4);
  float* isyn      = (float*)alloc((size_t)BB * NN * 4);
  signed char* S8a = (signed char*)alloc((size_t)BB * NN);
  signed char* S8b = (signed char*)alloc((size_t)BB * NN);
  float* mpart     = (float*)alloc((size_t)STEPS * BB * NBLK * 4);

  quant_kernel<<<(NN * NN) / 1024, 256, 0, stream>>>(Wrec, Ph, Pl, pk);

  void* args[] = {&Ph, &Pl, (void*)&obs, (void*)&Win, &pk};
  hipError_t cerr = hipLaunchCooperativeKernel((void*)brain2, dim3(NBLK),
                                               dim3(1024), args, 0, stream);
  if (cerr == hipSuccess) {
    final_pk<<<BB, 256, 0, stream>>>(pk, Wout, (float*)d_out);
  } else {
    // round-6 proven fallback
    init_kernel<<<(BB * NN) / 256, 256, 0, stream>>>(obs, Win, iin, v, isyn, S8a);
    for (int s = 0; s < STEPS; ++s) {
      const signed char* sin = (s & 1) ? S8b : S8a;
      signed char* sout      = (s & 1) ? S8a : S8b;
      step_kernel<<<NBLK, 1024, 0, stream>>>(sin, sout, Ph, Pl, iin, v, isyn,
                                             Wout, mpart, s);
    }
    final_mpart<<<BB, 256, 0, stream>>>(mpart, (float*)d_out);
  }
}

// Round 11
// 572.926 us; speedup vs baseline: 1.6684x; 1.0027x over previous
//
#include <hip/hip_runtime.h>
#include <math.h>

// SpikingPendulumBrain — single persistent kernel, data-sentinel sync.
//  * W_rec as two int8 planes (exact int32 MFMA; absmax 0.0 rounds 2/4/5/6/8/9/10).
//    Each wave holds its B fragments in 32 VGPRs all 50 steps (FETCH ~30MB).
//  * v/isyn/iin in registers. Spikes cross blocks bit-packed: pk[s][row][col]
//    u32, low 16 bits = spikes, HIGH 16 BITS ALWAYS 0 when written.
//  * SYNC = DATA SENTINEL: quant pre-fills pk[1..50] with 0xAAAA0000 and
//    zeroes pk[0]. Consumers poll words until the high half clears ->
//    store visibility IS the barrier (no flags, no vmcnt drain).
//  * ROUND 11: BATCHED polls. Round 10's poll8-per-pair serialized 8
//    dependent IC round-trips (~2us/step on the critical path). Now all 8
//    u64 loads issue back-to-back (one vmcnt drain), check sentinels after;
//    retry re-issues the whole batch (1 round trip per retry).
//  * All pk accesses agent-scope atomics (bypass non-coherent per-XCD L2s;
//    consumer L2 would otherwise cache the sentinel and spin forever).
//  * Fallback: round-6 proven multi-launch path if coop launch is rejected.

#define NN 4096
#define BB 64
#define STEPS 50
#define NBLK 256
#define NPB 16
#define PKROW 256                    // dwords per packed row (u32 per 16 cols)
#define PKSTEP (BB * PKROW)          // dwords per step buffer (64KB)

typedef __attribute__((ext_vector_type(4))) int i32x4;

static constexpr float WMAX_C = 0.16f;
static constexpr float QHI_C  = WMAX_C / 127.0f;
static constexpr float QLO_C  = QHI_C / 256.0f;
static constexpr float SYNDEC = (float)0.9801986733067553;  // exp(-0.1/5)
#define HIMASK 0xFFFF0000FFFF0000ull

// ---------------- one-time prep (re-run every call; ws is re-poisoned) -----

__global__ __launch_bounds__(256) void quant_kernel(const float* __restrict__ W,
                                                    signed char* __restrict__ Ph,
                                                    signed char* __restrict__ Pl,
                                                    unsigned* __restrict__ pk) {
  int idx = blockIdx.x * 256 + threadIdx.x;
  float4 w4 = reinterpret_cast<const float4*>(W)[idx];
  float w[4] = {w4.x, w4.y, w4.z, w4.w};
  signed char hi[4], lo[4];
#pragma unroll
  for (int i = 0; i < 4; i++) {
    float h = rintf(w[i] * (1.0f / QHI_C));
    h = fminf(127.0f, fmaxf(-127.0f, h));
    float r = fmaf(h, -QHI_C, w[i]);
    float l = rintf(r * (1.0f / QLO_C));
    l = fminf(127.0f, fmaxf(-127.0f, l));
    hi[i] = (signed char)(int)h;
    lo[i] = (signed char)(int)l;
  }
  reinterpret_cast<char4*>(Ph)[idx] = make_char4(hi[0], hi[1], hi[2], hi[3]);
  reinterpret_cast<char4*>(Pl)[idx] = make_char4(lo[0], lo[1], lo[2], lo[3]);
  // deterministic pk init: step 0 = all-zero spikes, steps 1..50 = sentinel.
  // Plain stores: kernel-boundary flush/inv makes them coherent for brain2.
  if (idx < (STEPS + 1) * PKSTEP)
    pk[idx] = (idx < PKSTEP) ? 0u : 0xAAAA0000u;
}

// ---------------- helpers ---------------------------------------------------

__device__ __forceinline__ i32x4 expand16(unsigned h) {
  // 16 bits -> 16 bytes (0/1): nibble q -> dword q via bit-spread multiply
  i32x4 a;
#pragma unroll
  for (int q = 0; q < 4; ++q) {
    unsigned nib = (h >> (4 * q)) & 0xFu;
    a[q] = (int)((nib * 0x00204081u) & 0x01010101u);
  }
  return a;
}

// ---------------- persistent brain kernel ----------------------------------
// 256 blocks x 1024 threads (16 waves, 1 block/CU). Block owns neurons
// [blk*16, +16), all 64 batch rows, full K. Wave w owns K-slice [w*256,+256)
// with B fragments in registers. Permuted k-map (A/B consistent, validated
// rounds 9/10): A word for (kc,lhi) = pk col w*16+lhi*4+kc; B fragment
// (kc,lhi) = slice bytes lhi*64 + kc*16.

__global__ __launch_bounds__(1024, 1) void brain2(
    const signed char* __restrict__ Ph,
    const signed char* __restrict__ Pl,
    const float* __restrict__ obs,
    const float* __restrict__ Win,
    unsigned* __restrict__ pk) {
  const int blk = blockIdx.x;
  const int n0  = blk * NPB;
  const int t   = threadIdx.x;
  const int lane = t & 63;
  const int w    = t >> 6;
  const int l15  = lane & 15, lhi = lane >> 4;
  const int ob   = t >> 4;          // owned batch row
  const int on   = t & 15;          // owned neuron (within block)

  __shared__ i32x4 red[16][4][64];  // 64KB cross-wave int32 partials

  float iin = 5.0f * (obs[ob * 2 + 0] * Win[(n0 + on) * 2 + 0] +
                      obs[ob * 2 + 1] * Win[(n0 + on) * 2 + 1]);
  float v = 0.0f, isyn = 0.0f;

  // B fragments held for the whole kernel (permuted k-map: lhi*64 + kc*16)
  const signed char* bhp = Ph + (size_t)(n0 + l15) * NN + w * 256 + lhi * 64;
  const signed char* blp = Pl + (size_t)(n0 + l15) * NN + w * 256 + lhi * 64;
  i32x4 Bh[4], Bl[4];
#pragma unroll
  for (int kc = 0; kc < 4; ++kc) {
    Bh[kc] = *reinterpret_cast<const i32x4*>(bhp + kc * 16);
    Bl[kc] = *reinterpret_cast<const i32x4*>(blp + kc * 16);
  }

  for (int s = 0; s < STEPS; ++s) {
    // ---- batched self-sync spike loads: issue all 8 u64s, check, retry ----
    const unsigned* ps = pk + (size_t)s * PKSTEP;
    const unsigned long long* pp[8];
#pragma unroll
    for (int mt = 0; mt < 4; ++mt) {
      const unsigned* pr = ps + (mt * 16 + l15) * PKROW + w * 16 + lhi * 4;
      pp[2 * mt]     = reinterpret_cast<const unsigned long long*>(pr);
      pp[2 * mt + 1] = reinterpret_cast<const unsigned long long*>(pr + 2);
    }
    unsigned long long u[8];
    for (;;) {
      unsigned long long msk = 0;
#pragma unroll
      for (int i = 0; i < 8; ++i) {
        u[i] = __hip_atomic_load(pp[i], __ATOMIC_RELAXED,
                                 __HIP_MEMORY_SCOPE_AGENT);
        msk |= u[i];
      }
      if (!(msk & HIMASK)) break;
      __builtin_amdgcn_s_sleep(1);
    }
    unsigned sb[4][4];
#pragma unroll
    for (int mt = 0; mt < 4; ++mt) {
      sb[mt][0] = (unsigned)u[2 * mt];
      sb[mt][1] = (unsigned)(u[2 * mt] >> 32);
      sb[mt][2] = (unsigned)u[2 * mt + 1];
      sb[mt][3] = (unsigned)(u[2 * mt + 1] >> 32);
    }

    // ---- MFMA: expand bits to i8 A-fragments in-register ----
    i32x4 acch[4], accl[4];
#pragma unroll
    for (int mt = 0; mt < 4; ++mt) {
      acch[mt] = (i32x4){0, 0, 0, 0};
      accl[mt] = (i32x4){0, 0, 0, 0};
    }
#pragma unroll
    for (int mt = 0; mt < 4; ++mt)
#pragma unroll
      for (int kc = 0; kc < 4; ++kc) {
        i32x4 a = expand16(sb[mt][kc]);
        acch[mt] = __builtin_amdgcn_mfma_i32_16x16x64_i8(a, Bh[kc], acch[mt], 0, 0, 0);
        accl[mt] = __builtin_amdgcn_mfma_i32_16x16x64_i8(a, Bl[kc], accl[mt], 0, 0, 0);
      }

    // ---- exact plane combine, dump to LDS ----
#pragma unroll
    for (int mt = 0; mt < 4; ++mt) {
      i32x4 vi;
#pragma unroll
      for (int r = 0; r < 4; ++r) vi[r] = (acch[mt][r] << 8) + accl[mt][r];
      red[w][mt][lane] = vi;
    }
    __syncthreads();

    // ---- LIF update on register state; publish spikes for step s+1 ----
    {
      const int mto = ob >> 4;
      const int li  = ((ob >> 2) & 3) * 16 + on;  // C/D: col=lane&15,row=(lane>>4)*4+r
      const int r   = ob & 3;
      int sum = 0;
#pragma unroll
      for (int ww = 0; ww < 16; ++ww) sum += red[ww][mto][li][r];

      float rec = QLO_C * (float)sum;
      float is = isyn * SYNDEC + iin + rec;
      float vv = v + (0.1f * (is - v)) / 20.0f;       // match ref op order
      bool sp = (vv >= 20.0f);
      v = sp ? 0.0f : vv;
      isyn = is;

      unsigned long long m = __ballot(sp);
      if ((lane & 15) == 0) {
        int j = lane >> 4;   // halfword j = row w*4 + j
        unsigned hw = (unsigned)((m >> (16 * j)) & 0xFFFFull);  // high 16 = 0
        __hip_atomic_store(pk + (size_t)(s + 1) * PKSTEP + (w * 4 + j) * PKROW + blk,
                           hw, __ATOMIC_RELAXED, __HIP_MEMORY_SCOPE_AGENT);
      }
    }
    __syncthreads();   // red[] WAR protection for next iteration
  }
}

// ---------------- epilogue from packed spike history -----------------------

__global__ __launch_bounds__(256) void final_pk(const unsigned* __restrict__ pk,
                                                const float* __restrict__ Wout,
                                                float* __restrict__ out) {
  int b = blockIdx.x, t = threadIdx.x;
  int lane = t & 63, wid = t >> 6;
  float wv[16];
#pragma unroll
  for (int i = 0; i < 16; ++i) wv[i] = Wout[t * 16 + i];
  __shared__ float red4[4];
  float acc = 0.0f;
  for (int s = 1; s <= STEPS; ++s) {
    unsigned h = __hip_atomic_load(pk + (size_t)s * PKSTEP + b * PKROW + t,
                                   __ATOMIC_RELAXED, __HIP_MEMORY_SCOPE_AGENT);
    float m = 0.0f;
#pragma unroll
    for (int i = 0; i < 16; ++i)
      if ((h >> i) & 1u) m += wv[i];
#pragma unroll
    for (int off = 32; off > 0; off >>= 1) m += __shfl_down(m, off);
    if (lane == 0) red4[wid] = m;
    __syncthreads();
    if (t == 0) acc += tanhf(red4[0] + red4[1] + red4[2] + red4[3]);
    __syncthreads();
  }
  if (t == 0) out[b] = acc * (1.0f / (float)STEPS);
}

// ================= round-6 proven fallback path ============================

__global__ __launch_bounds__(256) void init_kernel(const float* __restrict__ obs,
                                                   const float* __restrict__ Win,
                                                   float* __restrict__ iin,
                                                   float* __restrict__ v,
                                                   float* __restrict__ isyn,
                                                   signed char* __restrict__ S8a) {
  int idx = blockIdx.x * 256 + threadIdx.x;
  int b = idx >> 12, n = idx & (NN - 1);
  float o0 = obs[b * 2 + 0], o1 = obs[b * 2 + 1];
  float w0 = Win[n * 2 + 0], w1 = Win[n * 2 + 1];
  iin[idx]  = 5.0f * (o0 * w0 + o1 * w1);
  v[idx]    = 0.0f;
  isyn[idx] = 0.0f;
  S8a[idx]  = 0;
}

__global__ __launch_bounds__(1024) void step_kernel(
    const signed char* __restrict__ S8in,
    signed char* __restrict__ S8out,
    const signed char* __restrict__ Ph,
    const signed char* __restrict__ Pl,
    const float* __restrict__ iin,
    float* __restrict__ v,
    float* __restrict__ isyn,
    const float* __restrict__ Wout,
    float* __restrict__ mpart,
    int s) {
  const int blk = blockIdx.x;
  const int n0  = blk * NPB;
  const int t   = threadIdx.x;
  const int lane = t & 63;
  const int w    = t >> 6;
  const int l15  = lane & 15, lhi = lane >> 4;

  __shared__ i32x4 red[16][4][64];

  const int kbase = w * 256 + lhi * 16;
  const signed char* ap  = S8in + (size_t)l15 * NN + kbase;
  const signed char* bhp = Ph   + (size_t)(n0 + l15) * NN + kbase;
  const signed char* blp = Pl   + (size_t)(n0 + l15) * NN + kbase;

  i32x4 acch[4], accl[4];
#pragma unroll
  for (int mt = 0; mt < 4; ++mt) {
    acch[mt] = (i32x4){0, 0, 0, 0};
    accl[mt] = (i32x4){0, 0, 0, 0};
  }
#pragma unroll
  for (int kc = 0; kc < 4; ++kc) {
    i32x4 bh = *reinterpret_cast<const i32x4*>(bhp + kc * 64);
    i32x4 bl = *reinterpret_cast<const i32x4*>(blp + kc * 64);
#pragma unroll
    for (int mt = 0; mt < 4; ++mt) {
      i32x4 a = *reinterpret_cast<const i32x4*>(ap + kc * 64 + (size_t)mt * 16 * NN);
      acch[mt] = __builtin_amdgcn_mfma_i32_16x16x64_i8(a, bh, acch[mt], 0, 0, 0);
      accl[mt] = __builtin_amdgcn_mfma_i32_16x16x64_i8(a, bl, accl[mt], 0, 0, 0);
    }
  }
#pragma unroll
  for (int mt = 0; mt < 4; ++mt) {
    i32x4 vi;
#pragma unroll
    for (int r = 0; r < 4; ++r) vi[r] = (acch[mt][r] << 8) + accl[mt][r];
    red[w][mt][lane] = vi;
  }
  __syncthreads();
  {
    const int b  = t >> 4;
    const int nl = t & 15;
    const int mt = b >> 4;
    const int li = ((b >> 2) & 3) * 16 + nl;
    const int r  = b & 3;
    int sum = 0;
#pragma unroll
    for (int ww = 0; ww < 16; ++ww) sum += red[ww][mt][li][r];

    const size_t e = (size_t)b * NN + n0 + nl;
    float rec = QLO_C * (float)sum;
    float vold = v[e];
    float is = isyn[e] * SYNDEC + iin[e] + rec;
    float vv = vold + (0.1f * (is - vold)) / 20.0f;
    bool sp = (vv >= 20.0f);
    v[e]     = sp ? 0.0f : vv;
    isyn[e]  = is;
    S8out[e] = sp ? 1 : 0;

    float mot = sp ? Wout[n0 + nl] : 0.0f;
#pragma unroll
    for (int off = 1; off < 16; off <<= 1) mot += __shfl_xor(mot, off);
    if (nl == 0) mpart[((size_t)s * BB + b) * NBLK + blk] = mot;
  }
}

__global__ __launch_bounds__(256) void final_mpart(const float* __restrict__ mpart,
                                                   float* __restrict__ out) {
  int b = blockIdx.x;
  int t = threadIdx.x;
  int lane = t & 63, wid = t >> 6;
  __shared__ float red[4];
  float acc = 0.0f;
  for (int s = 0; s < STEPS; ++s) {
    float x = mpart[((size_t)s * BB + b) * NBLK + t];
#pragma unroll
    for (int off = 32; off > 0; off >>= 1) x += __shfl_down(x, off);
    if (lane == 0) red[wid] = x;
    __syncthreads();
    if (t == 0) acc += tanhf(red[0] + red[1] + red[2] + red[3]);
    __syncthreads();
  }
  if (t == 0) out[b] = acc * (1.0f / (float)STEPS);
}

// ---------------------------------------------------------------------------

extern "C" void kernel_launch(void* const* d_in, const int* in_sizes, int n_in,
                              void* d_out, int out_size, void* d_ws, size_t ws_size,
                              hipStream_t stream) {
  const float* obs  = (const float*)d_in[0];   // [64,2]
  const float* Win  = (const float*)d_in[1];   // [4096,2]
  const float* Wrec = (const float*)d_in[2];   // [4096,4096]
  const float* Wout = (const float*)d_in[3];   // [1,4096]

  char* ws = (char*)d_ws;
  size_t off = 0;
  auto alloc = [&](size_t bytes) -> void* {
    void* p = ws + off;
    off += (bytes + 255) & ~(size_t)255;
    return p;
  };
  signed char* Ph  = (signed char*)alloc((size_t)NN * NN);            // 16 MB
  signed char* Pl  = (signed char*)alloc((size_t)NN * NN);            // 16 MB
  unsigned* pk     = (unsigned*)alloc((size_t)(STEPS + 1) * PKSTEP * 4);  // 3.3 MB
  // fallback-path buffers
  float* iin       = (float*)alloc((size_t)BB * NN * 4);
  float* v         = (float*)alloc((size_t)BB * NN * 4);
  float* isyn      = (float*)alloc((size_t)BB * NN * 4);
  signed char* S8a = (signed char*)alloc((size_t)BB * NN);
  signed char* S8b = (signed char*)alloc((size_t)BB * NN);
  float* mpart     = (float*)alloc((size_t)STEPS * BB * NBLK * 4);

  quant_kernel<<<(NN * NN) / 1024, 256, 0, stream>>>(Wrec, Ph, Pl, pk);

  void* args[] = {&Ph, &Pl, (void*)&obs, (void*)&Win, &pk};
  hipError_t cerr = hipLaunchCooperativeKernel((void*)brain2, dim3(NBLK),
                                               dim3(1024), args, 0, stream);
  if (cerr == hipSuccess) {
    final_pk<<<BB, 256, 0, stream>>>(pk, Wout, (float*)d_out);
  } else {
    // round-6 proven fallback
    init_kernel<<<(BB * NN) / 256, 256, 0, stream>>>(obs, Win, iin, v, isyn, S8a);
    for (int s = 0; s < STEPS; ++s) {
      const signed char* sin = (s & 1) ? S8b : S8a;
      signed char* sout      = (s & 1) ? S8a : S8b;
      step_kernel<<<NBLK, 1024, 0, stream>>>(sin, sout, Ph, Pl, iin, v, isyn,
                                             Wout, mpart, s);
    }
    final_mpart<<<BB, 256, 0, stream>>>(mpart, (float*)d_out);
  }
}

// Round 12
// 507.739 us; speedup vs baseline: 1.8826x; 1.1284x over previous
//
#include <hip/hip_runtime.h>
#include <math.h>

// SpikingPendulumBrain — single persistent kernel, flag-gated L2 broadcast.
//  * W_rec as two int8 planes (exact int32 MFMA; absmax 0.0 rounds 2/4/5/6/8-11).
//    Each wave holds its B fragments in 32 VGPRs all 50 steps.
//  * v/isyn/iin in registers. Spikes cross blocks bit-packed 2 ROWS PER u32:
//    pk[s][rowpair][col] (32x256 u32 = 32KB/step).
//  * SYNC: per-(step,block) ready flags. Producer: sc1 data stores ->
//    vmcnt(0) -> __syncthreads -> relaxed sc1 flag store (no release fence;
//    round 8 showed release RMW costs ~13us in L2 writebacks). Consumer
//    wave polls only its 16 producers' flags (one 64B line, sc1).
//  * DATA loads are NORMAL cached loads: pk lines never enter L2 via writes
//    (sc1 stores bypass; init lines flushed at quant kernel end), so first
//    reader per XCD fills L2 and the other 31 blocks hit L2 -> IC traffic
//    drops 16MB/step -> ~0.25MB/step. Data written once before flag set ->
//    clean L2 copies always correct.
//  * Fallback: round-6 proven multi-launch path if coop launch is rejected.

#define NN 4096
#define BB 64
#define STEPS 50
#define NBLK 256
#define NPB 16
#define PKW 8192                     // dwords per step: 32 rowpairs x 256 cols
#define FLG 256                      // flags per step

typedef __attribute__((ext_vector_type(4))) int i32x4;

static constexpr float WMAX_C = 0.16f;
static constexpr float QHI_C  = WMAX_C / 127.0f;
static constexpr float QLO_C  = QHI_C / 256.0f;
static constexpr float SYNDEC = (float)0.9801986733067553;  // exp(-0.1/5)

// ---------------- one-time prep (re-run every call; ws is re-poisoned) -----

__global__ __launch_bounds__(256) void quant_kernel(const float* __restrict__ W,
                                                    signed char* __restrict__ Ph,
                                                    signed char* __restrict__ Pl,
                                                    unsigned* __restrict__ pk,
                                                    unsigned* __restrict__ flags) {
  int idx = blockIdx.x * 256 + threadIdx.x;
  float4 w4 = reinterpret_cast<const float4*>(W)[idx];
  float w[4] = {w4.x, w4.y, w4.z, w4.w};
  signed char hi[4], lo[4];
#pragma unroll
  for (int i = 0; i < 4; i++) {
    float h = rintf(w[i] * (1.0f / QHI_C));
    h = fminf(127.0f, fmaxf(-127.0f, h));
    float r = fmaf(h, -QHI_C, w[i]);
    float l = rintf(r * (1.0f / QLO_C));
    l = fminf(127.0f, fmaxf(-127.0f, l));
    hi[i] = (signed char)(int)h;
    lo[i] = (signed char)(int)l;
  }
  reinterpret_cast<char4*>(Ph)[idx] = make_char4(hi[0], hi[1], hi[2], hi[3]);
  reinterpret_cast<char4*>(Pl)[idx] = make_char4(lo[0], lo[1], lo[2], lo[3]);
  // step-0 spikes = 0; flags: step 0 ready, steps 1..50 not. Normal stores:
  // end-of-kernel writeback/invalidate makes them IC-resident and L2-clean.
  if (idx < PKW) pk[idx] = 0u;
  if (idx < (STEPS + 1) * FLG) flags[idx] = (idx < FLG) ? 1u : 0u;
}

// ---------------- helpers ---------------------------------------------------

__device__ __forceinline__ i32x4 expand16(unsigned h) {
  // 16 bits -> 16 bytes (0/1): nibble q -> dword q via bit-spread multiply
  i32x4 a;
#pragma unroll
  for (int q = 0; q < 4; ++q) {
    unsigned nib = (h >> (4 * q)) & 0xFu;
    a[q] = (int)((nib * 0x00204081u) & 0x01010101u);
  }
  return a;
}

// ---------------- persistent brain kernel ----------------------------------
// 256 blocks x 1024 threads (16 waves, 1 block/CU). Block owns neurons
// [blk*16, +16), all 64 batch rows, full K. Wave w owns K-slice [w*256,+256)
// with B fragments in registers. Permuted k-map (validated rounds 9-11):
// A word (kc,lhi) = pk col w*16+lhi*4+kc; B fragment (kc,lhi) = slice bytes
// lhi*64 + kc*16. Both carry k = w*256 + lhi*64 + kc*16 + i.

__global__ __launch_bounds__(1024, 1) void brain2(
    const signed char* __restrict__ Ph,
    const signed char* __restrict__ Pl,
    const float* __restrict__ obs,
    const float* __restrict__ Win,
    unsigned* __restrict__ pk,
    unsigned* __restrict__ flags) {
  const int blk = blockIdx.x;
  const int n0  = blk * NPB;
  const int t   = threadIdx.x;
  const int lane = t & 63;
  const int w    = t >> 6;
  const int l15  = lane & 15, lhi = lane >> 4;
  const int ob   = t >> 4;          // owned batch row
  const int on   = t & 15;          // owned neuron (within block)

  __shared__ i32x4 red[16][4][64];  // 64KB cross-wave int32 partials

  float iin = 5.0f * (obs[ob * 2 + 0] * Win[(n0 + on) * 2 + 0] +
                      obs[ob * 2 + 1] * Win[(n0 + on) * 2 + 1]);
  float v = 0.0f, isyn = 0.0f;

  // B fragments held for the whole kernel (permuted k-map: lhi*64 + kc*16)
  const signed char* bhp = Ph + (size_t)(n0 + l15) * NN + w * 256 + lhi * 64;
  const signed char* blp = Pl + (size_t)(n0 + l15) * NN + w * 256 + lhi * 64;
  i32x4 Bh[4], Bl[4];
#pragma unroll
  for (int kc = 0; kc < 4; ++kc) {
    Bh[kc] = *reinterpret_cast<const i32x4*>(bhp + kc * 16);
    Bl[kc] = *reinterpret_cast<const i32x4*>(blp + kc * 16);
  }

  for (int s = 0; s < STEPS; ++s) {
    // ---- wave-level wait: this wave's 16 producer blocks published step s --
    {
      const unsigned* fp = flags + s * FLG + w * 16;
      unsigned f = 1;
      for (;;) {
        if (lane < 16)
          f = __hip_atomic_load(fp + lane, __ATOMIC_RELAXED,
                                __HIP_MEMORY_SCOPE_AGENT);
        if (__all(f != 0)) break;
        __builtin_amdgcn_s_sleep(1);
      }
    }
    __builtin_amdgcn_sched_barrier(0);
    asm volatile("" ::: "memory");

    // ---- one-shot NORMAL data loads (L2 broadcast within XCD) ----
    const unsigned* ps = pk + (size_t)s * PKW;
    const int sh = (l15 & 1) * 16;
    unsigned sb[4][4];
#pragma unroll
    for (int mt = 0; mt < 4; ++mt) {
      i32x4 wd = *reinterpret_cast<const i32x4*>(
          ps + (mt * 8 + (l15 >> 1)) * 256 + w * 16 + lhi * 4);
#pragma unroll
      for (int kc = 0; kc < 4; ++kc)
        sb[mt][kc] = ((unsigned)wd[kc] >> sh) & 0xFFFFu;
    }

    // ---- MFMA: expand bits to i8 A-fragments in-register ----
    i32x4 acch[4], accl[4];
#pragma unroll
    for (int mt = 0; mt < 4; ++mt) {
      acch[mt] = (i32x4){0, 0, 0, 0};
      accl[mt] = (i32x4){0, 0, 0, 0};
    }
#pragma unroll
    for (int mt = 0; mt < 4; ++mt)
#pragma unroll
      for (int kc = 0; kc < 4; ++kc) {
        i32x4 a = expand16(sb[mt][kc]);
        acch[mt] = __builtin_amdgcn_mfma_i32_16x16x64_i8(a, Bh[kc], acch[mt], 0, 0, 0);
        accl[mt] = __builtin_amdgcn_mfma_i32_16x16x64_i8(a, Bl[kc], accl[mt], 0, 0, 0);
      }

    // ---- exact plane combine, dump to LDS ----
#pragma unroll
    for (int mt = 0; mt < 4; ++mt) {
      i32x4 vi;
#pragma unroll
      for (int r = 0; r < 4; ++r) vi[r] = (acch[mt][r] << 8) + accl[mt][r];
      red[w][mt][lane] = vi;
    }
    __syncthreads();

    // ---- LIF update on register state; publish spikes for step s+1 ----
    {
      const int mto = ob >> 4;
      const int li  = ((ob >> 2) & 3) * 16 + on;  // C/D: col=lane&15,row=(lane>>4)*4+r
      const int r   = ob & 3;
      int sum = 0;
#pragma unroll
      for (int ww = 0; ww < 16; ++ww) sum += red[ww][mto][li][r];

      float rec = QLO_C * (float)sum;
      float is = isyn * SYNDEC + iin + rec;
      float vv = v + (0.1f * (is - v)) / 20.0f;       // match ref op order
      bool sp = (vv >= 20.0f);
      v = sp ? 0.0f : vv;
      isyn = is;

      unsigned long long m = __ballot(sp);
      if ((lane & 31) == 0) {
        int jp = lane >> 5;  // rowpair w*2 + jp holds rows w*4+2jp, w*4+2jp+1
        unsigned word = (unsigned)(m >> (32 * jp));
        __hip_atomic_store(pk + (size_t)(s + 1) * PKW + (w * 2 + jp) * 256 + blk,
                           word, __ATOMIC_RELAXED, __HIP_MEMORY_SCOPE_AGENT);
      }
    }
    // ---- drain data stores, then flag = ready (relaxed; hw-ordered) ----
    asm volatile("s_waitcnt vmcnt(0)" ::: "memory");
    __syncthreads();   // also red[] WAR protection for next iteration
    if (t == 0)
      __hip_atomic_store(flags + (s + 1) * FLG + blk, 1u, __ATOMIC_RELAXED,
                         __HIP_MEMORY_SCOPE_AGENT);
  }
}

// ---------------- epilogue from packed spike history -----------------------

__global__ __launch_bounds__(256) void final_pk(const unsigned* __restrict__ pk,
                                                const float* __restrict__ Wout,
                                                float* __restrict__ out) {
  int b = blockIdx.x, t = threadIdx.x;   // t = col 0..255
  int lane = t & 63, wid = t >> 6;
  float wv[16];
#pragma unroll
  for (int i = 0; i < 16; ++i) wv[i] = Wout[t * 16 + i];
  __shared__ float red4[4];
  float acc = 0.0f;
  for (int s = 1; s <= STEPS; ++s) {
    unsigned word = pk[(size_t)s * PKW + (b >> 1) * 256 + t];
    unsigned h = (word >> ((b & 1) * 16)) & 0xFFFFu;
    float m = 0.0f;
#pragma unroll
    for (int i = 0; i < 16; ++i)
      if ((h >> i) & 1u) m += wv[i];
#pragma unroll
    for (int off = 32; off > 0; off >>= 1) m += __shfl_down(m, off);
    if (lane == 0) red4[wid] = m;
    __syncthreads();
    if (t == 0) acc += tanhf(red4[0] + red4[1] + red4[2] + red4[3]);
    __syncthreads();
  }
  if (t == 0) out[b] = acc * (1.0f / (float)STEPS);
}

// ================= round-6 proven fallback path ============================

__global__ __launch_bounds__(256) void init_kernel(const float* __restrict__ obs,
                                                   const float* __restrict__ Win,
                                                   float* __restrict__ iin,
                                                   float* __restrict__ v,
                                                   float* __restrict__ isyn,
                                                   signed char* __restrict__ S8a) {
  int idx = blockIdx.x * 256 + threadIdx.x;
  int b = idx >> 12, n = idx & (NN - 1);
  float o0 = obs[b * 2 + 0], o1 = obs[b * 2 + 1];
  float w0 = Win[n * 2 + 0], w1 = Win[n * 2 + 1];
  iin[idx]  = 5.0f * (o0 * w0 + o1 * w1);
  v[idx]    = 0.0f;
  isyn[idx] = 0.0f;
  S8a[idx]  = 0;
}

__global__ __launch_bounds__(1024) void step_kernel(
    const signed char* __restrict__ S8in,
    signed char* __restrict__ S8out,
    const signed char* __restrict__ Ph,
    const signed char* __restrict__ Pl,
    const float* __restrict__ iin,
    float* __restrict__ v,
    float* __restrict__ isyn,
    const float* __restrict__ Wout,
    float* __restrict__ mpart,
    int s) {
  const int blk = blockIdx.x;
  const int n0  = blk * NPB;
  const int t   = threadIdx.x;
  const int lane = t & 63;
  const int w    = t >> 6;
  const int l15  = lane & 15, lhi = lane >> 4;

  __shared__ i32x4 red[16][4][64];

  const int kbase = w * 256 + lhi * 16;
  const signed char* ap  = S8in + (size_t)l15 * NN + kbase;
  const signed char* bhp = Ph   + (size_t)(n0 + l15) * NN + kbase;
  const signed char* blp = Pl   + (size_t)(n0 + l15) * NN + kbase;

  i32x4 acch[4], accl[4];
#pragma unroll
  for (int mt = 0; mt < 4; ++mt) {
    acch[mt] = (i32x4){0, 0, 0, 0};
    accl[mt] = (i32x4){0, 0, 0, 0};
  }
#pragma unroll
  for (int kc = 0; kc < 4; ++kc) {
    i32x4 bh = *reinterpret_cast<const i32x4*>(bhp + kc * 64);
    i32x4 bl = *reinterpret_cast<const i32x4*>(blp + kc * 64);
#pragma unroll
    for (int mt = 0; mt < 4; ++mt) {
      i32x4 a = *reinterpret_cast<const i32x4*>(ap + kc * 64 + (size_t)mt * 16 * NN);
      acch[mt] = __builtin_amdgcn_mfma_i32_16x16x64_i8(a, bh, acch[mt], 0, 0, 0);
      accl[mt] = __builtin_amdgcn_mfma_i32_16x16x64_i8(a, bl, accl[mt], 0, 0, 0);
    }
  }
#pragma unroll
  for (int mt = 0; mt < 4; ++mt) {
    i32x4 vi;
#pragma unroll
    for (int r = 0; r < 4; ++r) vi[r] = (acch[mt][r] << 8) + accl[mt][r];
    red[w][mt][lane] = vi;
  }
  __syncthreads();
  {
    const int b  = t >> 4;
    const int nl = t & 15;
    const int mt = b >> 4;
    const int li = ((b >> 2) & 3) * 16 + nl;
    const int r  = b & 3;
    int sum = 0;
#pragma unroll
    for (int ww = 0; ww < 16; ++ww) sum += red[ww][mt][li][r];

    const size_t e = (size_t)b * NN + n0 + nl;
    float rec = QLO_C * (float)sum;
    float vold = v[e];
    float is = isyn[e] * SYNDEC + iin[e] + rec;
    float vv = vold + (0.1f * (is - vold)) / 20.0f;
    bool sp = (vv >= 20.0f);
    v[e]     = sp ? 0.0f : vv;
    isyn[e]  = is;
    S8out[e] = sp ? 1 : 0;

    float mot = sp ? Wout[n0 + nl] : 0.0f;
#pragma unroll
    for (int off = 1; off < 16; off <<= 1) mot += __shfl_xor(mot, off);
    if (nl == 0) mpart[((size_t)s * BB + b) * NBLK + blk] = mot;
  }
}

__global__ __launch_bounds__(256) void final_mpart(const float* __restrict__ mpart,
                                                   float* __restrict__ out) {
  int b = blockIdx.x;
  int t = threadIdx.x;
  int lane = t & 63, wid = t >> 6;
  __shared__ float red[4];
  float acc = 0.0f;
  for (int s = 0; s < STEPS; ++s) {
    float x = mpart[((size_t)s * BB + b) * NBLK + t];
#pragma unroll
    for (int off = 32; off > 0; off >>= 1) x += __shfl_down(x, off);
    if (lane == 0) red[wid] = x;
    __syncthreads();
    if (t == 0) acc += tanhf(red[0] + red[1] + red[2] + red[3]);
    __syncthreads();
  }
  if (t == 0) out[b] = acc * (1.0f / (float)STEPS);
}

// ---------------------------------------------------------------------------

extern "C" void kernel_launch(void* const* d_in, const int* in_sizes, int n_in,
                              void* d_out, int out_size, void* d_ws, size_t ws_size,
                              hipStream_t stream) {
  const float* obs  = (const float*)d_in[0];   // [64,2]
  const float* Win  = (const float*)d_in[1];   // [4096,2]
  const float* Wrec = (const float*)d_in[2];   // [4096,4096]
  const float* Wout = (const float*)d_in[3];   // [1,4096]

  char* ws = (char*)d_ws;
  size_t off = 0;
  auto alloc = [&](size_t bytes) -> void* {
    void* p = ws + off;
    off += (bytes + 255) & ~(size_t)255;
    return p;
  };
  signed char* Ph  = (signed char*)alloc((size_t)NN * NN);            // 16 MB
  signed char* Pl  = (signed char*)alloc((size_t)NN * NN);            // 16 MB
  unsigned* pk     = (unsigned*)alloc((size_t)(STEPS + 1) * PKW * 4); // 1.6 MB
  unsigned* flags  = (unsigned*)alloc((size_t)(STEPS + 1) * FLG * 4); // 52 KB
  // fallback-path buffers
  float* iin       = (float*)alloc((size_t)BB * NN * 4);
  float* v         = (float*)alloc((size_t)BB * NN * 4);
  float* isyn      = (float*)alloc((size_t)BB * NN * 4);
  signed char* S8a = (signed char*)alloc((size_t)BB * NN);
  signed char* S8b = (signed char*)alloc((size_t)BB * NN);
  float* mpart     = (float*)alloc((size_t)STEPS * BB * NBLK * 4);

  quant_kernel<<<(NN * NN) / 1024, 256, 0, stream>>>(Wrec, Ph, Pl, pk, flags);

  void* args[] = {&Ph, &Pl, (void*)&obs, (void*)&Win, &pk, &flags};
  hipError_t cerr = hipLaunchCooperativeKernel((void*)brain2, dim3(NBLK),
                                               dim3(1024), args, 0, stream);
  if (cerr == hipSuccess) {
    final_pk<<<BB, 256, 0, stream>>>(pk, Wout, (float*)d_out);
  } else {
    // round-6 proven fallback
    init_kernel<<<(BB * NN) / 256, 256, 0, stream>>>(obs, Win, iin, v, isyn, S8a);
    for (int s = 0; s < STEPS; ++s) {
      const signed char* sin = (s & 1) ? S8b : S8a;
      signed char* sout      = (s & 1) ? S8a : S8b;
      step_kernel<<<NBLK, 1024, 0, stream>>>(sin, sout, Ph, Pl, iin, v, isyn,
                                             Wout, mpart, s);
    }
    final_mpart<<<BB, 256, 0, stream>>>(mpart, (float*)d_out);
  }
}